// Round 4
// baseline (2077.970 us; speedup 1.0000x reference)
//
#include <hip/hip_runtime.h>
#include <hip/hip_bf16.h>
#include <hip/hip_fp16.h>
#include <stdint.h>

// Problem: B=4, C=64, H=W=64, L=4096.
// Outputs: y [4,64,64,64] (1048576 f32) then w [4,4096*64,3,3] (9437184 f32).
//
// Algebra: scores[(p,q),(y,x)] = sum_{a,b in -1..1} R[(p+a,q+b),(y+a,x+b)]
//          R[uv,st] = sum_c f[c,uv]*b[c,st]        (K=64 channel GEMM, exact fp32)
//          y[c,pq]  = sum_l P[pq,l]*b[c,l]         (bf16 MFMA)
//          P[pq,l]  = (1/9) sum_{a,b} attn[(pq+(a,b)), l+a*64+b]
//
// G1 tier (per-batch): R 64MB @0 | attn 32MB @64MB; P overlays R.
// ST fallback for ws < 96 MiB uses the simple kernels.

typedef unsigned short ushort_t;
typedef __attribute__((ext_vector_type(8))) short bf16x8;
typedef __attribute__((ext_vector_type(4))) float f32x4;

__device__ __forceinline__ float bf2f(ushort_t u){
  union { float f; uint32_t i; } v; v.i = ((uint32_t)u) << 16; return v.f;
}
__device__ __forceinline__ ushort_t f2bf(float f){
  union { float f; uint32_t i; } v; v.f = f;
  uint32_t x = v.i;
  return (ushort_t)((x + 0x7fffu + ((x >> 16) & 1u)) >> 16);  // RNE
}
// two packed bf16 (low, high of a u32) -> two floats; 2 VALU ops
__device__ __forceinline__ void bf2x2(uint32_t d, float& a, float& b){
  union { uint32_t u; float f; } x, y;
  x.u = d << 16; y.u = d & 0xffff0000u;
  a = x.f; b = y.f;
}

// ---- k_prep: write w output (exact patch copy of b) + zero the y region ----
__global__ __launch_bounds__(256) void k_prep(const float* __restrict__ bin,
                                              float* __restrict__ wout,
                                              float* __restrict__ yzero){
  int t = blockIdx.x * 256 + threadIdx.x;        // (bb, l, c), c fastest; 1048576 total
  yzero[t] = 0.f;
  int c  = t & 63;
  int l  = (t >> 6) & 4095;
  int bb = t >> 18;
  int y = l >> 6, x = l & 63;
  const float* src = bin + (((size_t)(bb * 64 + c)) << 12);
  float* dst = wout + (size_t)t * 9;
  #pragma unroll
  for (int i = 0; i < 3; i++){
    int yy = y + i - 1;
    #pragma unroll
    for (int j = 0; j < 3; j++){
      int xx = x + j - 1;
      float v = 0.f;
      if ((unsigned)yy < 64u && (unsigned)xx < 64u) v = src[(yy << 6) + xx];
      dst[i * 3 + j] = v;
    }
  }
}

// ---- k_rgemm: R[m,n] = sum_c f[c, m_base+m] * b[c, n]  (fp32 exact) ----
// 128x128 tile, K=64. Explicit float4 LDS reads (ds_read_b128).
__global__ __launch_bounds__(256, 2) void k_rgemm(const float* __restrict__ f,
                                                  const float* __restrict__ bin,
                                                  float* __restrict__ R,
                                                  int bt0, int m_base, int m_count,
                                                  unsigned long long r_stride){
  __shared__ float As[64][128];
  __shared__ float Bs[64][128];
  int bt = bt0 + blockIdx.z;
  int m0 = blockIdx.x << 7;
  int n0 = blockIdx.y << 7;
  const float* fb = f   + (((size_t)bt) << 18);
  const float* bb = bin + (((size_t)bt) << 18);
  float* Rb = R + (size_t)blockIdx.z * r_stride;
  int t = threadIdx.x;
  for (int idx = t; idx < 64 * 128; idx += 256){
    int c = idx >> 7, m = idx & 127;
    As[c][m] = (m0 + m < m_count) ? fb[(c << 12) + m_base + m0 + m] : 0.f;
    Bs[c][m] = bb[(c << 12) + n0 + m];
  }
  __syncthreads();
  int tx = t & 15, ty = t >> 4;
  float acc[8][8];
  #pragma unroll
  for (int i = 0; i < 8; i++)
    #pragma unroll
    for (int j = 0; j < 8; j++) acc[i][j] = 0.f;

  for (int c = 0; c < 64; c++){
    float4 a0 = *(const float4*)&As[c][(ty << 3)];
    float4 a1 = *(const float4*)&As[c][(ty << 3) + 4];
    float4 b0 = *(const float4*)&Bs[c][(tx << 2)];
    float4 b1 = *(const float4*)&Bs[c][64 + (tx << 2)];
    float av[8] = {a0.x, a0.y, a0.z, a0.w, a1.x, a1.y, a1.z, a1.w};
    float bv[8] = {b0.x, b0.y, b0.z, b0.w, b1.x, b1.y, b1.z, b1.w};
    #pragma unroll
    for (int i = 0; i < 8; i++)
      #pragma unroll
      for (int j = 0; j < 8; j++) acc[i][j] += av[i] * bv[j];
  }
  #pragma unroll
  for (int i = 0; i < 8; i++){
    int mrow = m0 + (ty << 3) + i;
    if (mrow < m_count){
      float* dst = Rb + ((size_t)mrow << 12) + n0;
      *(float4*)(dst + (tx << 2))      = make_float4(acc[i][0], acc[i][1], acc[i][2], acc[i][3]);
      *(float4*)(dst + 64 + (tx << 2)) = make_float4(acc[i][4], acc[i][5], acc[i][6], acc[i][7]);
    }
  }
}

// =====================================================================
// k_softmax3: fused single-pass stencil + online softmax.
// WG = 4x2 query tile (8 queries x 32 key-threads). Per 512-key chunk:
// stage 24 R rows (+-68 halo) into LDS (62KB -> 2 WG/CU), 9-tap stencil
// with shfl-up/down for the +-1 key edges (no conflicted b32 reads),
// s_rel kept as __half2 IN REGISTERS (64 VGPRs). Epilogue merges (m,l)
// over 32 lanes and writes bf16 attn. R fetched once.
// =====================================================================
__global__ __launch_bounds__(256, 2) void k_softmax3(const float* __restrict__ R,
                                                     ushort_t* __restrict__ attn){
  __shared__ float Rt[24][648];                 // 62208 B
  const int t  = threadIdx.x;
  const int bb = blockIdx.x;
  const int inner = bb >> 3;
  const int ty = ((bb & 7) << 1) | (inner & 1); // XCD band swizzle
  const int tx = inner >> 1;
  const int p0 = ty << 2, q0 = tx << 1;
  const int qi = t >> 5, kt = t & 31;
  const int pi = qi >> 1, qj = qi & 1;
  const int ktx = kt & 15;

  float M = -3.0e38f, L = 0.f;
  float mref[8];
  __half2 sh[8][8];                             // s_rel per chunk, registers
  float4 rbuf[16];

  // prefetch chunk 0
  #pragma unroll
  for (int i = 0; i < 16; i++){
    int idx = t + (i << 8);
    float4 v = make_float4(0.f, 0.f, 0.f, 0.f);
    if (idx < 3888){
      unsigned r = (unsigned)idx / 162u;
      int fo = idx - (int)r * 162;
      int rp = p0 - 1 + (int)(r >> 2);
      int rq = q0 - 1 + (int)(r & 3);
      int kg = -68 + (fo << 2);
      if ((unsigned)rp < 64u && (unsigned)rq < 64u && (unsigned)kg <= 4092u)
        v = *(const float4*)(R + (((size_t)((rp << 6) + rq)) << 12) + kg);
    }
    rbuf[i] = v;
  }

  #pragma unroll
  for (int c = 0; c < 8; c++){
    __syncthreads();
    #pragma unroll
    for (int i = 0; i < 16; i++){
      int idx = t + (i << 8);
      if (idx < 3888) ((float4*)&Rt[0][0])[idx] = rbuf[i];
    }
    __syncthreads();
    if (c < 7){
      const int k0 = (c + 1) << 9;
      #pragma unroll
      for (int i = 0; i < 16; i++){
        int idx = t + (i << 8);
        float4 v = make_float4(0.f, 0.f, 0.f, 0.f);
        if (idx < 3888){
          unsigned r = (unsigned)idx / 162u;
          int fo = idx - (int)r * 162;
          int rp = p0 - 1 + (int)(r >> 2);
          int rq = q0 - 1 + (int)(r & 3);
          int kg = k0 - 68 + (fo << 2);
          if ((unsigned)rp < 64u && (unsigned)rq < 64u && (unsigned)kg <= 4092u)
            v = *(const float4*)(R + (((size_t)((rp << 6) + rq)) << 12) + kg);
        }
        rbuf[i] = v;
      }
    }
    // 9-tap stencil from LDS; edges via cross-lane shfl
    float4 sv[4];
    #pragma unroll
    for (int j = 0; j < 4; j++){
      int y = (c << 3) + (j << 1) + (kt >> 4);
      int sa0 = (j << 7) + (kt << 2) + 68;
      float4 s = make_float4(0.f, 0.f, 0.f, 0.f);
      #pragma unroll
      for (int a = -1; a <= 1; a++){
        if ((unsigned)(y + a) < 64u){
          int rb = (pi + 1 + a) << 2;
          int sa = sa0 + (a << 6);
          float4 A0 = *(const float4*)&Rt[rb + qj][sa];
          float4 A1 = *(const float4*)&Rt[rb + qj + 1][sa];
          float4 A2 = *(const float4*)&Rt[rb + qj + 2][sa];
          float Lv = __shfl_up(A0.w, 1);    // prev lane's r0[sa-1]
          float Rv = __shfl_down(A2.x, 1);  // next lane's r2[sa+4]
          s.x += (ktx == 0 ? 0.f : Lv) + A1.x + A2.y;
          s.y += A0.x + A1.y + A2.z;
          s.z += A0.y + A1.z + A2.w;
          s.w += A0.z + A1.w + (ktx == 15 ? 0.f : Rv);
        }
      }
      s.x *= 10.f; s.y *= 10.f; s.z *= 10.f; s.w *= 10.f;
      sv[j] = s;
    }
    // online softmax update
    float mc = M;
    #pragma unroll
    for (int j = 0; j < 4; j++)
      mc = fmaxf(mc, fmaxf(fmaxf(sv[j].x, sv[j].y), fmaxf(sv[j].z, sv[j].w)));
    float lnew = L * __expf(M - mc);
    #pragma unroll
    for (int j = 0; j < 4; j++)
      lnew += __expf(sv[j].x - mc) + __expf(sv[j].y - mc)
            + __expf(sv[j].z - mc) + __expf(sv[j].w - mc);
    L = lnew; M = mc; mref[c] = mc;
    #pragma unroll
    for (int j = 0; j < 4; j++){
      sh[c][(j << 1)]     = __floats2half2_rn(sv[j].x - mc, sv[j].y - mc);
      sh[c][(j << 1) + 1] = __floats2half2_rn(sv[j].z - mc, sv[j].w - mc);
    }
  }
  // merge (M,L) across the 32 lanes of this query
  #pragma unroll
  for (int off = 1; off < 32; off <<= 1){
    float m2 = __shfl_xor(M, off);
    float l2 = __shfl_xor(L, off);
    float mn = fmaxf(M, m2);
    L = L * __expf(M - mn) + l2 * __expf(m2 - mn);
    M = mn;
  }
  float invL = 1.0f / L;
  int row = ((p0 + pi) << 6) + q0 + qj;
  ushort_t* arow = attn + ((size_t)row << 12);
  #pragma unroll
  for (int c = 0; c < 8; c++){
    float d = mref[c] - M;
    #pragma unroll
    for (int j = 0; j < 4; j++){
      float2 lo = __half22float2(sh[c][(j << 1)]);
      float2 hi = __half22float2(sh[c][(j << 1) + 1]);
      ushort4 o;
      o.x = f2bf(__expf(lo.x + d) * invL);
      o.y = f2bf(__expf(lo.y + d) * invL);
      o.z = f2bf(__expf(hi.x + d) * invL);
      o.w = f2bf(__expf(hi.y + d) * invL);
      *(ushort4*)&arow[(c << 9) + (j << 7) + (kt << 2)] = o;
    }
  }
}

// =====================================================================
// k_pstencil3: P = (1/9)*stencil9(attn). Same tiling; attn staged RAW
// bf16 in LDS (31KB), b64 stencil reads, shfl edges, bf16 P out.
// =====================================================================
__global__ __launch_bounds__(256, 2) void k_pstencil3(const ushort_t* __restrict__ attn,
                                                      ushort_t* __restrict__ P){
  __shared__ ushort_t At[24][648];              // 31104 B
  const int t  = threadIdx.x;
  const int bb = blockIdx.x;
  const int inner = bb >> 3;
  const int ty = ((bb & 7) << 1) | (inner & 1);
  const int tx = inner >> 1;
  const int p0 = ty << 2, q0 = tx << 1;
  const int qi = t >> 5, kt = t & 31;
  const int pi = qi >> 1, qj = qi & 1;
  const int ktx = kt & 15;

  int row = ((p0 + pi) << 6) + q0 + qj;
  ushort_t* prow = P + ((size_t)row << 12);
  const float inv9 = 1.0f / 9.0f;

  uint2 rbuf[16];
  #pragma unroll
  for (int i = 0; i < 16; i++){
    int idx = t + (i << 8);
    uint2 v = make_uint2(0u, 0u);
    if (idx < 3888){
      unsigned r = (unsigned)idx / 162u;
      int fo = idx - (int)r * 162;
      int rp = p0 - 1 + (int)(r >> 2);
      int rq = q0 - 1 + (int)(r & 3);
      int kg = -68 + (fo << 2);
      if ((unsigned)rp < 64u && (unsigned)rq < 64u && (unsigned)kg <= 4092u)
        v = *(const uint2*)(attn + (((size_t)((rp << 6) + rq)) << 12) + kg);
    }
    rbuf[i] = v;
  }

  #pragma unroll
  for (int c = 0; c < 8; c++){
    __syncthreads();
    #pragma unroll
    for (int i = 0; i < 16; i++){
      int idx = t + (i << 8);
      if (idx < 3888) ((uint2*)&At[0][0])[idx] = rbuf[i];
    }
    __syncthreads();
    if (c < 7){
      const int k0 = (c + 1) << 9;
      #pragma unroll
      for (int i = 0; i < 16; i++){
        int idx = t + (i << 8);
        uint2 v = make_uint2(0u, 0u);
        if (idx < 3888){
          unsigned r = (unsigned)idx / 162u;
          int fo = idx - (int)r * 162;
          int rp = p0 - 1 + (int)(r >> 2);
          int rq = q0 - 1 + (int)(r & 3);
          int kg = k0 - 68 + (fo << 2);
          if ((unsigned)rp < 64u && (unsigned)rq < 64u && (unsigned)kg <= 4092u)
            v = *(const uint2*)(attn + (((size_t)((rp << 6) + rq)) << 12) + kg);
        }
        rbuf[i] = v;
      }
    }
    #pragma unroll
    for (int j = 0; j < 4; j++){
      int y = (c << 3) + (j << 1) + (kt >> 4);
      int sa0 = (j << 7) + (kt << 2) + 68;
      float4 s = make_float4(0.f, 0.f, 0.f, 0.f);
      #pragma unroll
      for (int a = -1; a <= 1; a++){
        if ((unsigned)(y + a) < 64u){
          int rb = (pi + 1 + a) << 2;
          int sa = sa0 + (a << 6);
          uint2 U0 = *(const uint2*)&At[rb + qj][sa];
          uint2 U1 = *(const uint2*)&At[rb + qj + 1][sa];
          uint2 U2 = *(const uint2*)&At[rb + qj + 2][sa];
          float4 A0, A1, A2;
          bf2x2(U0.x, A0.x, A0.y); bf2x2(U0.y, A0.z, A0.w);
          bf2x2(U1.x, A1.x, A1.y); bf2x2(U1.y, A1.z, A1.w);
          bf2x2(U2.x, A2.x, A2.y); bf2x2(U2.y, A2.z, A2.w);
          float Lv = __shfl_up(A0.w, 1);
          float Rv = __shfl_down(A2.x, 1);
          s.x += (ktx == 0 ? 0.f : Lv) + A1.x + A2.y;
          s.y += A0.x + A1.y + A2.z;
          s.z += A0.y + A1.z + A2.w;
          s.w += A0.z + A1.w + (ktx == 15 ? 0.f : Rv);
        }
      }
      ushort4 o;
      o.x = f2bf(s.x * inv9);
      o.y = f2bf(s.y * inv9);
      o.z = f2bf(s.z * inv9);
      o.w = f2bf(s.w * inv9);
      *(ushort4*)&prow[(c << 9) + (j << 7) + (kt << 2)] = o;
    }
  }
}

// ---- legacy simple kernels for the ST (small-ws) fallback tier ----
__global__ __launch_bounds__(256) void k_softmax(const float* __restrict__ R,
                                                 ushort_t* __restrict__ attn,
                                                 int p_base, int m_base,
                                                 unsigned long long r_stride,
                                                 unsigned long long a_stride){
  int row = (p_base << 6) + blockIdx.x;
  int p = row >> 6, q = row & 63;
  const float* Rz = R + (size_t)blockIdx.y * r_stride;
  int t = threadIdx.x;
  float s[16];
  #pragma unroll
  for (int k = 0; k < 16; k++) s[k] = 0.f;
  #pragma unroll
  for (int a = -1; a <= 1; a++){
    if ((unsigned)(p + a) >= 64u) continue;
    #pragma unroll
    for (int b2 = -1; b2 <= 1; b2++){
      if ((unsigned)(q + b2) >= 64u) continue;
      const float* Rrow = Rz + ((size_t)(((p + a) << 6) + (q + b2) - m_base) << 12);
      int shift = a * 64 + b2;
      #pragma unroll
      for (int k = 0; k < 16; k++){
        int l = (k << 8) + t;
        int y = l >> 6, x = l & 63;
        if ((unsigned)(y + a) < 64u && (unsigned)(x + b2) < 64u)
          s[k] += Rrow[l + shift];
      }
    }
  }
  float m = -1e30f;
  #pragma unroll
  for (int k = 0; k < 16; k++){ s[k] *= 10.f; m = fmaxf(m, s[k]); }
  #pragma unroll
  for (int off = 32; off; off >>= 1) m = fmaxf(m, __shfl_xor(m, off));
  __shared__ float redm[4];
  __shared__ float reds[4];
  int wv = t >> 6;
  if ((t & 63) == 0) redm[wv] = m;
  __syncthreads();
  m = fmaxf(fmaxf(redm[0], redm[1]), fmaxf(redm[2], redm[3]));
  float e[16]; float sum = 0.f;
  #pragma unroll
  for (int k = 0; k < 16; k++){ e[k] = __expf(s[k] - m); sum += e[k]; }
  #pragma unroll
  for (int off = 32; off; off >>= 1) sum += __shfl_xor(sum, off);
  if ((t & 63) == 0) reds[wv] = sum;
  __syncthreads();
  sum = reds[0] + reds[1] + reds[2] + reds[3];
  float inv = 1.0f / sum;
  ushort_t* arow = attn + (size_t)blockIdx.y * a_stride + ((size_t)row << 12);
  #pragma unroll
  for (int k = 0; k < 16; k++) arow[(k << 8) + t] = f2bf(e[k] * inv);
}

__global__ __launch_bounds__(256) void k_pstencil(const ushort_t* __restrict__ attn,
                                                  ushort_t* __restrict__ P,
                                                  unsigned long long a_stride,
                                                  unsigned long long p_stride){
  int row = blockIdx.x;
  int p = row >> 6, q = row & 63;
  const ushort_t* az = attn + (size_t)blockIdx.y * a_stride;
  int t = threadIdx.x;
  float s[16];
  #pragma unroll
  for (int k = 0; k < 16; k++) s[k] = 0.f;
  #pragma unroll
  for (int a = -1; a <= 1; a++){
    if ((unsigned)(p + a) >= 64u) continue;
    #pragma unroll
    for (int b2 = -1; b2 <= 1; b2++){
      if ((unsigned)(q + b2) >= 64u) continue;
      const ushort_t* arow = az + ((size_t)(((p + a) << 6) + (q + b2)) << 12);
      int shift = a * 64 + b2;
      #pragma unroll
      for (int k = 0; k < 16; k++){
        int l = (k << 8) + t;
        int y = l >> 6, x = l & 63;
        if ((unsigned)(y + a) < 64u && (unsigned)(x + b2) < 64u)
          s[k] += bf2f(arow[l + shift]);
      }
    }
  }
  ushort_t* prow = P + (size_t)blockIdx.y * p_stride + ((size_t)row << 12);
  const float inv9 = 1.0f / 9.0f;
  #pragma unroll
  for (int k = 0; k < 16; k++) prow[(k << 8) + t] = f2bf(s[k] * inv9);
}

// ---- k_ygemm: y[c,pq] = sum_l P[pq,l]*b[c,l]; 16x16x32 bf16 MFMA; K-split 4 + atomics ----
__global__ __launch_bounds__(256) void k_ygemm(const float* __restrict__ bin,
                                               const ushort_t* __restrict__ P,
                                               float* __restrict__ y,
                                               int bt0, unsigned long long p_stride){
  __shared__ ushort_t SB[64][72];
  __shared__ ushort_t SP[64][72];
  int bt  = bt0 + blockIdx.z;
  int pq0 = blockIdx.x << 6;
  int k0  = blockIdx.y << 10;
  int t = threadIdx.x;
  int lane = t & 63, wv = t >> 6;
  const float*    bbase = bin + (((size_t)bt) << 18);
  const ushort_t* Pbase = P + (size_t)blockIdx.z * p_stride + ((size_t)pq0 << 12);

  f32x4 acc[4];
  #pragma unroll
  for (int cb = 0; cb < 4; cb++) acc[cb] = (f32x4){0.f, 0.f, 0.f, 0.f};

  for (int kb = k0; kb < k0 + 1024; kb += 64){
    for (int idx = t; idx < 1024; idx += 256){
      int c = idx >> 4, g = idx & 15;
      float4 v = *(const float4*)(bbase + (c << 12) + kb + (g << 2));
      ushort_t* d = &SB[c][g << 2];
      d[0] = f2bf(v.x); d[1] = f2bf(v.y); d[2] = f2bf(v.z); d[3] = f2bf(v.w);
    }
    for (int idx = t; idx < 1024; idx += 256){
      int r = idx >> 4, g = idx & 15;
      *(uint64_t*)&SP[r][g << 2] =
          *(const uint64_t*)(Pbase + (((size_t)r) << 12) + kb + (g << 2));
    }
    __syncthreads();
    #pragma unroll
    for (int ks = 0; ks < 64; ks += 32){
      bf16x8 pf = *(const bf16x8*)&SP[(wv << 4) + (lane & 15)][ks + ((lane >> 4) << 3)];
      #pragma unroll
      for (int cb = 0; cb < 4; cb++){
        bf16x8 bf = *(const bf16x8*)&SB[(cb << 4) + (lane & 15)][ks + ((lane >> 4) << 3)];
        acc[cb] = __builtin_amdgcn_mfma_f32_16x16x32_bf16(bf, pf, acc[cb], 0, 0, 0);
      }
    }
    __syncthreads();
  }
  int quad = lane >> 4;
  int pql = pq0 + (wv << 4) + (lane & 15);
  #pragma unroll
  for (int cb = 0; cb < 4; cb++)
    #pragma unroll
    for (int r = 0; r < 4; r++){
      int c = (cb << 4) + (quad << 2) + r;
      atomicAdd(&y[(((size_t)(bt * 64 + c)) << 12) + pql], acc[cb][r]);
    }
}

extern "C" void kernel_launch(void* const* d_in, const int* in_sizes, int n_in,
                              void* d_out, int out_size, void* d_ws, size_t ws_size,
                              hipStream_t stream){
  const float* f = (const float*)d_in[0];
  const float* b = (const float*)d_in[1];
  float* out  = (float*)d_out;
  float* yout = out;
  float* wout = out + 1048576;

  const size_t RB = 4096ull * 4096 * 4;   // 64 MiB fp32 R per batch
  const size_t AB = 4096ull * 4096 * 2;   // 32 MiB bf16 attn/P per batch

  k_prep<<<4096, 256, 0, stream>>>(b, wout, yout);   // also zeroes y

  if (ws_size >= RB + AB) {
    // G1: one batch at a time. R @0 | attn @64MB; P overlays R.
    float*    R    = (float*)d_ws;
    ushort_t* attn = (ushort_t*)((char*)d_ws + RB);
    ushort_t* P    = (ushort_t*)d_ws;
    for (int bt = 0; bt < 4; bt++){
      k_rgemm    <<<dim3(32, 32, 1), 256, 0, stream>>>(f, b, R, bt, 0, 4096, 0);
      k_softmax3 <<<512, 256, 0, stream>>>(R, attn);
      k_pstencil3<<<512, 256, 0, stream>>>(attn, P);
      k_ygemm    <<<dim3(64, 4, 1), 256, 0, stream>>>(b, P, yout, bt, 0);
    }
  } else {
    // ST fallback: attn 32MB @0; R stream blocks then P @32MB. Floor 64MiB.
    ushort_t* attn = (ushort_t*)d_ws;
    float*    R    = (float*)((char*)d_ws + AB);
    ushort_t* P    = (ushort_t*)((char*)d_ws + AB);
    for (int bt = 0; bt < 4; bt++){
      for (int p0 = 0; p0 < 64; p0 += 16){
        int lo = (p0 > 0) ? p0 - 1 : 0;
        int hi = (p0 + 16 < 64) ? p0 + 16 : 63;
        int m_base = lo << 6, m_count = (hi - lo + 1) << 6;
        k_rgemm  <<<dim3((m_count + 127) >> 7, 32, 1), 256, 0, stream>>>(
                      f, b, R, bt, m_base, m_count, 0);
        k_softmax<<<dim3(1024, 1), 256, 0, stream>>>(R, attn, p0, m_base, 0, 0);
      }
      k_pstencil<<<dim3(4096, 1), 256, 0, stream>>>(attn, P, 0, 0);
      k_ygemm   <<<dim3(64, 4, 1), 256, 0, stream>>>(b, P, yout, bt, 0);
    }
  }
}

// Round 6
// 701.554 us; speedup vs baseline: 2.9620x; 2.9620x over previous
//
#include <hip/hip_runtime.h>
#include <hip/hip_bf16.h>
#include <hip/hip_fp16.h>
#include <stdint.h>

// Problem: B=4, C=64, H=W=64, L=4096.
// Outputs: y [4,64,64,64] (1048576 f32) then w [4,4096*64,3,3] (9437184 f32).
//
// Algebra: scores[(p,q),(y,x)] = sum_{a,b in -1..1} R[(p+a,q+b),(y+a,x+b)]
//          R[uv,st] = sum_c f[c,uv]*b[c,st]        (K=64 channel GEMM, exact fp32)
//          y[c,pq]  = sum_l P[pq,l]*b[c,l]         (bf16 MFMA)
//          P[pq,l]  = (1/9) sum_{a,b} attn[(pq+(a,b)), l+a*64+b]
//
// attn is stored UNNORMALIZED per 512-key chunk: exp(s - mref_c), plus a
// per-(row,chunk) scale table scale[row][c] = exp(mref_c - M)/L.
// ROUND-6 FIX: k_pstencil5 applies the scale PER TAP-KEY'S CHUNK at LDS
// staging time (round 5 wrongly used the output chunk's scale for the
// +-68-key halo, which belongs to adjacent chunks -> absmax 1.16).
//
// G1 tier (per-batch): R 64MB @0 | attn 32MB @64MB | scale 128KB @96MB; P overlays R.

typedef unsigned short ushort_t;
typedef __attribute__((ext_vector_type(8))) short bf16x8;
typedef __attribute__((ext_vector_type(4))) float f32x4;

__device__ __forceinline__ float bf2f(ushort_t u){
  union { float f; uint32_t i; } v; v.i = ((uint32_t)u) << 16; return v.f;
}
__device__ __forceinline__ ushort_t f2bf(float f){
  union { float f; uint32_t i; } v; v.f = f;
  uint32_t x = v.i;
  return (ushort_t)((x + 0x7fffu + ((x >> 16) & 1u)) >> 16);  // RNE
}

// ---- k_prep: write w output (exact patch copy of b) + zero the y region ----
__global__ __launch_bounds__(256) void k_prep(const float* __restrict__ bin,
                                              float* __restrict__ wout,
                                              float* __restrict__ yzero){
  int t = blockIdx.x * 256 + threadIdx.x;        // (bb, l, c), c fastest; 1048576 total
  yzero[t] = 0.f;
  int c  = t & 63;
  int l  = (t >> 6) & 4095;
  int bb = t >> 18;
  int y = l >> 6, x = l & 63;
  const float* src = bin + (((size_t)(bb * 64 + c)) << 12);
  float* dst = wout + (size_t)t * 9;
  #pragma unroll
  for (int i = 0; i < 3; i++){
    int yy = y + i - 1;
    #pragma unroll
    for (int j = 0; j < 3; j++){
      int xx = x + j - 1;
      float v = 0.f;
      if ((unsigned)yy < 64u && (unsigned)xx < 64u) v = src[(yy << 6) + xx];
      dst[i * 3 + j] = v;
    }
  }
}

// ---- k_rgemm: R[m,n] = sum_c f[c,m] * b[c,n]  (fp32 exact), 128x128 tile ----
__global__ __launch_bounds__(256, 2) void k_rgemm(const float* __restrict__ f,
                                                  const float* __restrict__ bin,
                                                  float* __restrict__ R,
                                                  int bt0){
  __shared__ float As[64][128];
  __shared__ float Bs[64][128];
  int bt = bt0 + blockIdx.z;
  int m0 = blockIdx.x << 7;
  int n0 = blockIdx.y << 7;
  const float* fb = f   + (((size_t)bt) << 18);
  const float* bb = bin + (((size_t)bt) << 18);
  int t = threadIdx.x;
  for (int idx = t; idx < 64 * 128; idx += 256){
    int c = idx >> 7, m = idx & 127;
    As[c][m] = fb[(c << 12) + m0 + m];
    Bs[c][m] = bb[(c << 12) + n0 + m];
  }
  __syncthreads();
  int tx = t & 15, ty = t >> 4;
  float acc[8][8];
  #pragma unroll
  for (int i = 0; i < 8; i++)
    #pragma unroll
    for (int j = 0; j < 8; j++) acc[i][j] = 0.f;

  for (int c = 0; c < 64; c++){
    float4 a0 = *(const float4*)&As[c][(ty << 3)];
    float4 a1 = *(const float4*)&As[c][(ty << 3) + 4];
    float4 b0 = *(const float4*)&Bs[c][(tx << 2)];
    float4 b1 = *(const float4*)&Bs[c][64 + (tx << 2)];
    float av[8] = {a0.x, a0.y, a0.z, a0.w, a1.x, a1.y, a1.z, a1.w};
    float bv[8] = {b0.x, b0.y, b0.z, b0.w, b1.x, b1.y, b1.z, b1.w};
    #pragma unroll
    for (int i = 0; i < 8; i++)
      #pragma unroll
      for (int j = 0; j < 8; j++) acc[i][j] += av[i] * bv[j];
  }
  #pragma unroll
  for (int i = 0; i < 8; i++){
    float* dst = R + ((size_t)(m0 + (ty << 3) + i) << 12) + n0;
    *(float4*)(dst + (tx << 2))      = make_float4(acc[i][0], acc[i][1], acc[i][2], acc[i][3]);
    *(float4*)(dst + 64 + (tx << 2)) = make_float4(acc[i][4], acc[i][5], acc[i][6], acc[i][7]);
  }
}

// =====================================================================
// k_softmax4: fused single-pass stencil + online softmax, no stash.
// WG = 4x2 query tile (8 queries x 32 key-threads). Per 512-key chunk:
// stage 24 R rows (+-68 halo) into LDS (62KB -> 2 WG/CU), 9-tap stencil
// with shfl edges, lane-uniform chunk max mc, write exp(s - mc) bf16
// immediately. Epilogue: scale[row][c] = exp(mref_c - M)/L.
// =====================================================================
__global__ __launch_bounds__(256, 2) void k_softmax4(const float* __restrict__ R,
                                                     ushort_t* __restrict__ attn,
                                                     float* __restrict__ scale){
  __shared__ float Rt[24][648];                 // 62208 B
  const int t  = threadIdx.x;
  const int bb = blockIdx.x;
  const int inner = bb >> 3;
  const int ty = ((bb & 7) << 1) | (inner & 1); // XCD band swizzle
  const int tx = inner >> 1;
  const int p0 = ty << 2, q0 = tx << 1;
  const int qi = t >> 5, kt = t & 31;
  const int pi = qi >> 1, qj = qi & 1;
  const int ktx = kt & 15;

  float M = -3.0e38f, L = 0.f;
  float mref[8];
  float4 rbuf[16];

  int row = ((p0 + pi) << 6) + q0 + qj;
  ushort_t* arow = attn + ((size_t)row << 12);

  // prefetch chunk 0
  #pragma unroll
  for (int i = 0; i < 16; i++){
    int idx = t + (i << 8);
    float4 v = make_float4(0.f, 0.f, 0.f, 0.f);
    if (idx < 3888){
      unsigned r = (unsigned)idx / 162u;
      int fo = idx - (int)r * 162;
      int rp = p0 - 1 + (int)(r >> 2);
      int rq = q0 - 1 + (int)(r & 3);
      int kg = -68 + (fo << 2);
      if ((unsigned)rp < 64u && (unsigned)rq < 64u && (unsigned)kg <= 4092u)
        v = *(const float4*)(R + (((size_t)((rp << 6) + rq)) << 12) + kg);
    }
    rbuf[i] = v;
  }

  #pragma unroll
  for (int c = 0; c < 8; c++){
    __syncthreads();
    #pragma unroll
    for (int i = 0; i < 16; i++){
      int idx = t + (i << 8);
      if (idx < 3888) ((float4*)&Rt[0][0])[idx] = rbuf[i];
    }
    __syncthreads();
    if (c < 7){
      const int k0 = (c + 1) << 9;
      #pragma unroll
      for (int i = 0; i < 16; i++){
        int idx = t + (i << 8);
        float4 v = make_float4(0.f, 0.f, 0.f, 0.f);
        if (idx < 3888){
          unsigned r = (unsigned)idx / 162u;
          int fo = idx - (int)r * 162;
          int rp = p0 - 1 + (int)(r >> 2);
          int rq = q0 - 1 + (int)(r & 3);
          int kg = k0 - 68 + (fo << 2);
          if ((unsigned)rp < 64u && (unsigned)rq < 64u && (unsigned)kg <= 4092u)
            v = *(const float4*)(R + (((size_t)((rp << 6) + rq)) << 12) + kg);
        }
        rbuf[i] = v;
      }
    }
    // 9-tap stencil from LDS; +-1 key edges via cross-lane shfl
    float4 sv[4];
    #pragma unroll
    for (int j = 0; j < 4; j++){
      int y = (c << 3) + (j << 1) + (kt >> 4);
      int sa0 = (j << 7) + (kt << 2) + 68;
      float4 s = make_float4(0.f, 0.f, 0.f, 0.f);
      #pragma unroll
      for (int a = -1; a <= 1; a++){
        if ((unsigned)(y + a) < 64u){
          int rb = (pi + 1 + a) << 2;
          int sa = sa0 + (a << 6);
          float4 A0 = *(const float4*)&Rt[rb + qj][sa];
          float4 A1 = *(const float4*)&Rt[rb + qj + 1][sa];
          float4 A2 = *(const float4*)&Rt[rb + qj + 2][sa];
          float Lv = __shfl_up(A0.w, 1);
          float Rv = __shfl_down(A2.x, 1);
          s.x += (ktx == 0 ? 0.f : Lv) + A1.x + A2.y;
          s.y += A0.x + A1.y + A2.z;
          s.z += A0.y + A1.z + A2.w;
          s.w += A0.z + A1.w + (ktx == 15 ? 0.f : Rv);
        }
      }
      s.x *= 10.f; s.y *= 10.f; s.z *= 10.f; s.w *= 10.f;
      sv[j] = s;
    }
    // lane-uniform chunk max over this query's 32 lanes
    float mc = M;
    #pragma unroll
    for (int j = 0; j < 4; j++)
      mc = fmaxf(mc, fmaxf(fmaxf(sv[j].x, sv[j].y), fmaxf(sv[j].z, sv[j].w)));
    #pragma unroll
    for (int off = 1; off < 32; off <<= 1) mc = fmaxf(mc, __shfl_xor(mc, off));
    // online update + immediate unnormalized bf16 store
    float lnew = L * __expf(M - mc);
    #pragma unroll
    for (int j = 0; j < 4; j++){
      float ex = __expf(sv[j].x - mc), ey = __expf(sv[j].y - mc);
      float ez = __expf(sv[j].z - mc), ew = __expf(sv[j].w - mc);
      lnew += ex + ey + ez + ew;
      ushort4 o; o.x = f2bf(ex); o.y = f2bf(ey); o.z = f2bf(ez); o.w = f2bf(ew);
      *(ushort4*)&arow[(c << 9) + (j << 7) + (kt << 2)] = o;
    }
    L = lnew; M = mc; mref[c] = mc;
  }
  // L per-lane partial; M/mref lane-uniform -> plain cross-lane sum
  #pragma unroll
  for (int off = 1; off < 32; off <<= 1) L += __shfl_xor(L, off);
  if (kt == 0){
    float invL = 1.0f / L;
    float4 s0, s1;
    s0.x = __expf(mref[0] - M) * invL; s0.y = __expf(mref[1] - M) * invL;
    s0.z = __expf(mref[2] - M) * invL; s0.w = __expf(mref[3] - M) * invL;
    s1.x = __expf(mref[4] - M) * invL; s1.y = __expf(mref[5] - M) * invL;
    s1.z = __expf(mref[6] - M) * invL; s1.w = __expf(mref[7] - M) * invL;
    *(float4*)&scale[(row << 3)]     = s0;
    *(float4*)&scale[(row << 3) + 4] = s1;
  }
}

// =====================================================================
// k_pstencil5: P = (1/9)*stencil9(attn_unnorm * scale). Scale applied at
// LDS staging time PER TAP-KEY'S CHUNK (each 4-key group is chunk-pure:
// keys and the 512 boundary are 4-aligned). Staged fp32 62KB + 768B Sc
// -> 2 WG/CU. Stencil body = plain adds + shfl edges.
// =====================================================================
__global__ __launch_bounds__(256, 2) void k_pstencil5(const ushort_t* __restrict__ attn,
                                                      const float* __restrict__ scale,
                                                      ushort_t* __restrict__ P){
  __shared__ float At[24][648];                 // 62208 B
  __shared__ float Sc[24][8];                   // 768 B
  const int t  = threadIdx.x;
  const int bb = blockIdx.x;
  const int inner = bb >> 3;
  const int ty = ((bb & 7) << 1) | (inner & 1);
  const int tx = inner >> 1;
  const int p0 = ty << 2, q0 = tx << 1;
  const int qi = t >> 5, kt = t & 31;
  const int pi = qi >> 1, qj = qi & 1;
  const int ktx = kt & 15;

  int row = ((p0 + pi) << 6) + q0 + qj;
  ushort_t* prow = P + ((size_t)row << 12);
  const float inv9 = 1.0f / 9.0f;

  if (t < 192){
    int r = t >> 3, cc = t & 7;
    int rp = p0 - 1 + (r >> 2);
    int rq = q0 - 1 + (r & 3);
    float v = 0.f;
    if ((unsigned)rp < 64u && (unsigned)rq < 64u)
      v = scale[(((rp << 6) + rq) << 3) + cc];
    Sc[r][cc] = v;
  }

  uint2 rbuf[16];
  #pragma unroll
  for (int i = 0; i < 16; i++){
    int idx = t + (i << 8);
    uint2 v = make_uint2(0u, 0u);
    if (idx < 3888){
      unsigned r = (unsigned)idx / 162u;
      int fo = idx - (int)r * 162;
      int rp = p0 - 1 + (int)(r >> 2);
      int rq = q0 - 1 + (int)(r & 3);
      int kg = -68 + (fo << 2);
      if ((unsigned)rp < 64u && (unsigned)rq < 64u && (unsigned)kg <= 4092u)
        v = *(const uint2*)(attn + (((size_t)((rp << 6) + rq)) << 12) + kg);
    }
    rbuf[i] = v;
  }

  #pragma unroll
  for (int c = 0; c < 8; c++){
    __syncthreads();   // first iter also fences the Sc stores
    #pragma unroll
    for (int i = 0; i < 16; i++){
      int idx = t + (i << 8);
      if (idx < 3888){
        unsigned r = (unsigned)idx / 162u;
        int fo = idx - (int)r * 162;
        // chunk of this 4-key group (clamped; OOB keys are zero anyway)
        int key = (c << 9) - 68 + (fo << 2);
        key = key < 0 ? 0 : (key > 4095 ? 4095 : key);
        float sc = Sc[r][key >> 9];
        uint2 u = rbuf[i];
        float4 w;
        { union { uint32_t q; float f; } a_, b_;
          a_.q = u.x << 16; b_.q = u.x & 0xffff0000u; w.x = a_.f * sc; w.y = b_.f * sc; }
        { union { uint32_t q; float f; } a_, b_;
          a_.q = u.y << 16; b_.q = u.y & 0xffff0000u; w.z = a_.f * sc; w.w = b_.f * sc; }
        ((float4*)&At[0][0])[idx] = w;
      }
    }
    __syncthreads();
    if (c < 7){
      const int k0 = (c + 1) << 9;
      #pragma unroll
      for (int i = 0; i < 16; i++){
        int idx = t + (i << 8);
        uint2 v = make_uint2(0u, 0u);
        if (idx < 3888){
          unsigned r = (unsigned)idx / 162u;
          int fo = idx - (int)r * 162;
          int rp = p0 - 1 + (int)(r >> 2);
          int rq = q0 - 1 + (int)(r & 3);
          int kg = k0 - 68 + (fo << 2);
          if ((unsigned)rp < 64u && (unsigned)rq < 64u && (unsigned)kg <= 4092u)
            v = *(const uint2*)(attn + (((size_t)((rp << 6) + rq)) << 12) + kg);
        }
        rbuf[i] = v;
      }
    }
    #pragma unroll
    for (int j = 0; j < 4; j++){
      int y = (c << 3) + (j << 1) + (kt >> 4);
      int sa0 = (j << 7) + (kt << 2) + 68;
      float4 s = make_float4(0.f, 0.f, 0.f, 0.f);
      #pragma unroll
      for (int a = -1; a <= 1; a++){
        if ((unsigned)(y + a) < 64u){
          int rb = (pi + 1 + a) << 2;
          int sa = sa0 + (a << 6);
          float4 A0 = *(const float4*)&At[rb + qj][sa];
          float4 A1 = *(const float4*)&At[rb + qj + 1][sa];
          float4 A2 = *(const float4*)&At[rb + qj + 2][sa];
          float Lv = __shfl_up(A0.w, 1);
          float Rv = __shfl_down(A2.x, 1);
          s.x += (ktx == 0 ? 0.f : Lv) + A1.x + A2.y;
          s.y += A0.x + A1.y + A2.z;
          s.z += A0.y + A1.z + A2.w;
          s.w += A0.z + A1.w + (ktx == 15 ? 0.f : Rv);
        }
      }
      ushort4 o;
      o.x = f2bf(s.x * inv9);
      o.y = f2bf(s.y * inv9);
      o.z = f2bf(s.z * inv9);
      o.w = f2bf(s.w * inv9);
      *(ushort4*)&prow[(c << 9) + (j << 7) + (kt << 2)] = o;
    }
  }
}

// ---- k_ygemm: y[c,pq] = sum_l P[pq,l]*b[c,l]; 16x16x32 bf16 MFMA; K-split 4 + atomics ----
__global__ __launch_bounds__(256) void k_ygemm(const float* __restrict__ bin,
                                               const ushort_t* __restrict__ P,
                                               float* __restrict__ y,
                                               int bt0){
  __shared__ ushort_t SB[64][72];
  __shared__ ushort_t SP[64][72];
  int bt  = bt0 + blockIdx.z;
  int pq0 = blockIdx.x << 6;
  int k0  = blockIdx.y << 10;
  int t = threadIdx.x;
  int lane = t & 63, wv = t >> 6;
  const float*    bbase = bin + (((size_t)bt) << 18);
  const ushort_t* Pbase = P + ((size_t)pq0 << 12);

  f32x4 acc[4];
  #pragma unroll
  for (int cb = 0; cb < 4; cb++) acc[cb] = (f32x4){0.f, 0.f, 0.f, 0.f};

  for (int kb = k0; kb < k0 + 1024; kb += 64){
    for (int idx = t; idx < 1024; idx += 256){
      int c = idx >> 4, g = idx & 15;
      float4 v = *(const float4*)(bbase + (c << 12) + kb + (g << 2));
      ushort_t* d = &SB[c][g << 2];
      d[0] = f2bf(v.x); d[1] = f2bf(v.y); d[2] = f2bf(v.z); d[3] = f2bf(v.w);
    }
    for (int idx = t; idx < 1024; idx += 256){
      int r = idx >> 4, g = idx & 15;
      *(uint64_t*)&SP[r][g << 2] =
          *(const uint64_t*)(Pbase + (((size_t)r) << 12) + kb + (g << 2));
    }
    __syncthreads();
    #pragma unroll
    for (int ks = 0; ks < 64; ks += 32){
      bf16x8 pf = *(const bf16x8*)&SP[(wv << 4) + (lane & 15)][ks + ((lane >> 4) << 3)];
      #pragma unroll
      for (int cb = 0; cb < 4; cb++){
        bf16x8 bf = *(const bf16x8*)&SB[(cb << 4) + (lane & 15)][ks + ((lane >> 4) << 3)];
        acc[cb] = __builtin_amdgcn_mfma_f32_16x16x32_bf16(bf, pf, acc[cb], 0, 0, 0);
      }
    }
    __syncthreads();
  }
  int quad = lane >> 4;
  int pql = pq0 + (wv << 4) + (lane & 15);
  #pragma unroll
  for (int cb = 0; cb < 4; cb++)
    #pragma unroll
    for (int r = 0; r < 4; r++){
      int c = (cb << 4) + (quad << 2) + r;
      atomicAdd(&y[(((size_t)(bt * 64 + c)) << 12) + pql], acc[cb][r]);
    }
}

extern "C" void kernel_launch(void* const* d_in, const int* in_sizes, int n_in,
                              void* d_out, int out_size, void* d_ws, size_t ws_size,
                              hipStream_t stream){
  const float* f = (const float*)d_in[0];
  const float* b = (const float*)d_in[1];
  float* out  = (float*)d_out;
  float* yout = out;
  float* wout = out + 1048576;

  const size_t RB  = 4096ull * 4096 * 4;   // 64 MiB fp32 R per batch
  const size_t AB  = 4096ull * 4096 * 2;   // 32 MiB bf16 attn/P per batch
  const size_t SCB = 4096ull * 8 * 4;      // 128 KiB scale table
  (void)SCB;

  k_prep<<<4096, 256, 0, stream>>>(b, wout, yout);   // also zeroes y

  // G1: one batch at a time. R @0 | attn @64MB | scale @96MB; P overlays R.
  float*    R     = (float*)d_ws;
  ushort_t* attn  = (ushort_t*)((char*)d_ws + RB);
  float*    scale = (float*)((char*)d_ws + RB + AB);
  ushort_t* P     = (ushort_t*)d_ws;
  for (int bt = 0; bt < 4; bt++){
    k_rgemm    <<<dim3(32, 32, 1), 256, 0, stream>>>(f, b, R, bt);
    k_softmax4 <<<512, 256, 0, stream>>>(R, attn, scale);
    k_pstencil5<<<512, 256, 0, stream>>>(attn, scale, P);
    k_ygemm    <<<dim3(64, 4, 1), 256, 0, stream>>>(b, P, yout, bt);
  }
}

// Round 7
// 663.004 us; speedup vs baseline: 3.1342x; 1.0581x over previous
//
#include <hip/hip_runtime.h>
#include <hip/hip_bf16.h>
#include <hip/hip_fp16.h>
#include <stdint.h>

// Problem: B=4, C=64, H=W=64, L=4096.
// Outputs: y [4,64,64,64] (1048576 f32) then w [4,4096*64,3,3] (9437184 f32).
//
// Algebra: scores[(p,q),(y,x)] = sum_{a,b in -1..1} R[(p+a,q+b),(y+a,x+b)]
//          R[uv,st] = sum_c f[c,uv]*b[c,st]        (K=64 channel GEMM, exact fp32)
//          y[c,pq]  = sum_l P[pq,l]*b[c,l]         (bf16 MFMA, barrier-free direct loads)
//          P[pq,l]  = (1/9) sum_{a,b} attn[(pq+(a,b)), l+a*64+b]
//
// attn stored UNNORMALIZED per 512-key chunk: exp(s - mref_c), plus
// scale[row][c] = exp(mref_c - M)/L; k_pstencil5 applies scale per
// TAP-KEY'S chunk at LDS staging time.
//
// G1 tier (per-batch): R 64MB @0 | attn 32MB @64MB | scale 128KB @96MB; P overlays R.

typedef unsigned short ushort_t;
typedef __attribute__((ext_vector_type(8))) short bf16x8;
typedef __attribute__((ext_vector_type(4))) float f32x4;

__device__ __forceinline__ float bf2f(ushort_t u){
  union { float f; uint32_t i; } v; v.i = ((uint32_t)u) << 16; return v.f;
}
__device__ __forceinline__ ushort_t f2bf(float f){
  union { float f; uint32_t i; } v; v.f = f;
  uint32_t x = v.i;
  return (ushort_t)((x + 0x7fffu + ((x >> 16) & 1u)) >> 16);  // RNE
}

// ---- k_prep: write w output (exact patch copy of b) + zero the y region ----
__global__ __launch_bounds__(256) void k_prep(const float* __restrict__ bin,
                                              float* __restrict__ wout,
                                              float* __restrict__ yzero){
  int t = blockIdx.x * 256 + threadIdx.x;        // (bb, l, c), c fastest; 1048576 total
  yzero[t] = 0.f;
  int c  = t & 63;
  int l  = (t >> 6) & 4095;
  int bb = t >> 18;
  int y = l >> 6, x = l & 63;
  const float* src = bin + (((size_t)(bb * 64 + c)) << 12);
  float* dst = wout + (size_t)t * 9;
  #pragma unroll
  for (int i = 0; i < 3; i++){
    int yy = y + i - 1;
    #pragma unroll
    for (int j = 0; j < 3; j++){
      int xx = x + j - 1;
      float v = 0.f;
      if ((unsigned)yy < 64u && (unsigned)xx < 64u) v = src[(yy << 6) + xx];
      dst[i * 3 + j] = v;
    }
  }
}

// ---- k_rgemm: R[m,n] = sum_c f[c,m] * b[c,n]  (fp32 exact), 128x128 tile ----
__global__ __launch_bounds__(256, 2) void k_rgemm(const float* __restrict__ f,
                                                  const float* __restrict__ bin,
                                                  float* __restrict__ R,
                                                  int bt0){
  __shared__ float As[64][128];
  __shared__ float Bs[64][128];
  int bt = bt0 + blockIdx.z;
  int m0 = blockIdx.x << 7;
  int n0 = blockIdx.y << 7;
  const float* fb = f   + (((size_t)bt) << 18);
  const float* bb = bin + (((size_t)bt) << 18);
  int t = threadIdx.x;
  for (int idx = t; idx < 64 * 128; idx += 256){
    int c = idx >> 7, m = idx & 127;
    As[c][m] = fb[(c << 12) + m0 + m];
    Bs[c][m] = bb[(c << 12) + n0 + m];
  }
  __syncthreads();
  int tx = t & 15, ty = t >> 4;
  float acc[8][8];
  #pragma unroll
  for (int i = 0; i < 8; i++)
    #pragma unroll
    for (int j = 0; j < 8; j++) acc[i][j] = 0.f;

  for (int c = 0; c < 64; c++){
    float4 a0 = *(const float4*)&As[c][(ty << 3)];
    float4 a1 = *(const float4*)&As[c][(ty << 3) + 4];
    float4 b0 = *(const float4*)&Bs[c][(tx << 2)];
    float4 b1 = *(const float4*)&Bs[c][64 + (tx << 2)];
    float av[8] = {a0.x, a0.y, a0.z, a0.w, a1.x, a1.y, a1.z, a1.w};
    float bv[8] = {b0.x, b0.y, b0.z, b0.w, b1.x, b1.y, b1.z, b1.w};
    #pragma unroll
    for (int i = 0; i < 8; i++)
      #pragma unroll
      for (int j = 0; j < 8; j++) acc[i][j] += av[i] * bv[j];
  }
  #pragma unroll
  for (int i = 0; i < 8; i++){
    float* dst = R + ((size_t)(m0 + (ty << 3) + i) << 12) + n0;
    *(float4*)(dst + (tx << 2))      = make_float4(acc[i][0], acc[i][1], acc[i][2], acc[i][3]);
    *(float4*)(dst + 64 + (tx << 2)) = make_float4(acc[i][4], acc[i][5], acc[i][6], acc[i][7]);
  }
}

// =====================================================================
// k_softmax4: fused single-pass stencil + online softmax, no stash.
// WG = 4x2 query tile (8 queries x 32 key-threads). Per 512-key chunk:
// stage 24 R rows (+-68 halo) into LDS (62KB -> 2 WG/CU), 9-tap stencil
// with shfl edges, lane-uniform chunk max mc, write exp(s - mc) bf16
// immediately. Epilogue: scale[row][c] = exp(mref_c - M)/L.
// =====================================================================
__global__ __launch_bounds__(256, 2) void k_softmax4(const float* __restrict__ R,
                                                     ushort_t* __restrict__ attn,
                                                     float* __restrict__ scale){
  __shared__ float Rt[24][648];                 // 62208 B
  const int t  = threadIdx.x;
  const int bb = blockIdx.x;
  const int inner = bb >> 3;
  const int ty = ((bb & 7) << 1) | (inner & 1); // XCD band swizzle
  const int tx = inner >> 1;
  const int p0 = ty << 2, q0 = tx << 1;
  const int qi = t >> 5, kt = t & 31;
  const int pi = qi >> 1, qj = qi & 1;
  const int ktx = kt & 15;

  float M = -3.0e38f, L = 0.f;
  float mref[8];
  float4 rbuf[16];

  int row = ((p0 + pi) << 6) + q0 + qj;
  ushort_t* arow = attn + ((size_t)row << 12);

  // prefetch chunk 0
  #pragma unroll
  for (int i = 0; i < 16; i++){
    int idx = t + (i << 8);
    float4 v = make_float4(0.f, 0.f, 0.f, 0.f);
    if (idx < 3888){
      unsigned r = (unsigned)idx / 162u;
      int fo = idx - (int)r * 162;
      int rp = p0 - 1 + (int)(r >> 2);
      int rq = q0 - 1 + (int)(r & 3);
      int kg = -68 + (fo << 2);
      if ((unsigned)rp < 64u && (unsigned)rq < 64u && (unsigned)kg <= 4092u)
        v = *(const float4*)(R + (((size_t)((rp << 6) + rq)) << 12) + kg);
    }
    rbuf[i] = v;
  }

  #pragma unroll
  for (int c = 0; c < 8; c++){
    __syncthreads();
    #pragma unroll
    for (int i = 0; i < 16; i++){
      int idx = t + (i << 8);
      if (idx < 3888) ((float4*)&Rt[0][0])[idx] = rbuf[i];
    }
    __syncthreads();
    if (c < 7){
      const int k0 = (c + 1) << 9;
      #pragma unroll
      for (int i = 0; i < 16; i++){
        int idx = t + (i << 8);
        float4 v = make_float4(0.f, 0.f, 0.f, 0.f);
        if (idx < 3888){
          unsigned r = (unsigned)idx / 162u;
          int fo = idx - (int)r * 162;
          int rp = p0 - 1 + (int)(r >> 2);
          int rq = q0 - 1 + (int)(r & 3);
          int kg = k0 - 68 + (fo << 2);
          if ((unsigned)rp < 64u && (unsigned)rq < 64u && (unsigned)kg <= 4092u)
            v = *(const float4*)(R + (((size_t)((rp << 6) + rq)) << 12) + kg);
        }
        rbuf[i] = v;
      }
    }
    // 9-tap stencil from LDS; +-1 key edges via cross-lane shfl
    float4 sv[4];
    #pragma unroll
    for (int j = 0; j < 4; j++){
      int y = (c << 3) + (j << 1) + (kt >> 4);
      int sa0 = (j << 7) + (kt << 2) + 68;
      float4 s = make_float4(0.f, 0.f, 0.f, 0.f);
      #pragma unroll
      for (int a = -1; a <= 1; a++){
        if ((unsigned)(y + a) < 64u){
          int rb = (pi + 1 + a) << 2;
          int sa = sa0 + (a << 6);
          float4 A0 = *(const float4*)&Rt[rb + qj][sa];
          float4 A1 = *(const float4*)&Rt[rb + qj + 1][sa];
          float4 A2 = *(const float4*)&Rt[rb + qj + 2][sa];
          float Lv = __shfl_up(A0.w, 1);
          float Rv = __shfl_down(A2.x, 1);
          s.x += (ktx == 0 ? 0.f : Lv) + A1.x + A2.y;
          s.y += A0.x + A1.y + A2.z;
          s.z += A0.y + A1.z + A2.w;
          s.w += A0.z + A1.w + (ktx == 15 ? 0.f : Rv);
        }
      }
      s.x *= 10.f; s.y *= 10.f; s.z *= 10.f; s.w *= 10.f;
      sv[j] = s;
    }
    // lane-uniform chunk max over this query's 32 lanes
    float mc = M;
    #pragma unroll
    for (int j = 0; j < 4; j++)
      mc = fmaxf(mc, fmaxf(fmaxf(sv[j].x, sv[j].y), fmaxf(sv[j].z, sv[j].w)));
    #pragma unroll
    for (int off = 1; off < 32; off <<= 1) mc = fmaxf(mc, __shfl_xor(mc, off));
    // online update + immediate unnormalized bf16 store
    float lnew = L * __expf(M - mc);
    #pragma unroll
    for (int j = 0; j < 4; j++){
      float ex = __expf(sv[j].x - mc), ey = __expf(sv[j].y - mc);
      float ez = __expf(sv[j].z - mc), ew = __expf(sv[j].w - mc);
      lnew += ex + ey + ez + ew;
      ushort4 o; o.x = f2bf(ex); o.y = f2bf(ey); o.z = f2bf(ez); o.w = f2bf(ew);
      *(ushort4*)&arow[(c << 9) + (j << 7) + (kt << 2)] = o;
    }
    L = lnew; M = mc; mref[c] = mc;
  }
  // L per-lane partial; M/mref lane-uniform -> plain cross-lane sum
  #pragma unroll
  for (int off = 1; off < 32; off <<= 1) L += __shfl_xor(L, off);
  if (kt == 0){
    float invL = 1.0f / L;
    float4 s0, s1;
    s0.x = __expf(mref[0] - M) * invL; s0.y = __expf(mref[1] - M) * invL;
    s0.z = __expf(mref[2] - M) * invL; s0.w = __expf(mref[3] - M) * invL;
    s1.x = __expf(mref[4] - M) * invL; s1.y = __expf(mref[5] - M) * invL;
    s1.z = __expf(mref[6] - M) * invL; s1.w = __expf(mref[7] - M) * invL;
    *(float4*)&scale[(row << 3)]     = s0;
    *(float4*)&scale[(row << 3) + 4] = s1;
  }
}

// =====================================================================
// k_pstencil5: P = (1/9)*stencil9(attn_unnorm * scale). Scale applied at
// LDS staging time PER TAP-KEY'S CHUNK (each 4-key group is chunk-pure).
// Staged fp32 62KB + 768B Sc -> 2 WG/CU. Stencil = plain adds + shfl edges.
// =====================================================================
__global__ __launch_bounds__(256, 2) void k_pstencil5(const ushort_t* __restrict__ attn,
                                                      const float* __restrict__ scale,
                                                      ushort_t* __restrict__ P){
  __shared__ float At[24][648];                 // 62208 B
  __shared__ float Sc[24][8];                   // 768 B
  const int t  = threadIdx.x;
  const int bb = blockIdx.x;
  const int inner = bb >> 3;
  const int ty = ((bb & 7) << 1) | (inner & 1);
  const int tx = inner >> 1;
  const int p0 = ty << 2, q0 = tx << 1;
  const int qi = t >> 5, kt = t & 31;
  const int pi = qi >> 1, qj = qi & 1;
  const int ktx = kt & 15;

  int row = ((p0 + pi) << 6) + q0 + qj;
  ushort_t* prow = P + ((size_t)row << 12);
  const float inv9 = 1.0f / 9.0f;

  if (t < 192){
    int r = t >> 3, cc = t & 7;
    int rp = p0 - 1 + (r >> 2);
    int rq = q0 - 1 + (r & 3);
    float v = 0.f;
    if ((unsigned)rp < 64u && (unsigned)rq < 64u)
      v = scale[(((rp << 6) + rq) << 3) + cc];
    Sc[r][cc] = v;
  }

  uint2 rbuf[16];
  #pragma unroll
  for (int i = 0; i < 16; i++){
    int idx = t + (i << 8);
    uint2 v = make_uint2(0u, 0u);
    if (idx < 3888){
      unsigned r = (unsigned)idx / 162u;
      int fo = idx - (int)r * 162;
      int rp = p0 - 1 + (int)(r >> 2);
      int rq = q0 - 1 + (int)(r & 3);
      int kg = -68 + (fo << 2);
      if ((unsigned)rp < 64u && (unsigned)rq < 64u && (unsigned)kg <= 4092u)
        v = *(const uint2*)(attn + (((size_t)((rp << 6) + rq)) << 12) + kg);
    }
    rbuf[i] = v;
  }

  #pragma unroll
  for (int c = 0; c < 8; c++){
    __syncthreads();   // first iter also fences the Sc stores
    #pragma unroll
    for (int i = 0; i < 16; i++){
      int idx = t + (i << 8);
      if (idx < 3888){
        unsigned r = (unsigned)idx / 162u;
        int fo = idx - (int)r * 162;
        int key = (c << 9) - 68 + (fo << 2);
        key = key < 0 ? 0 : (key > 4095 ? 4095 : key);
        float sc = Sc[r][key >> 9];
        uint2 u = rbuf[i];
        float4 w;
        { union { uint32_t q; float f; } a_, b_;
          a_.q = u.x << 16; b_.q = u.x & 0xffff0000u; w.x = a_.f * sc; w.y = b_.f * sc; }
        { union { uint32_t q; float f; } a_, b_;
          a_.q = u.y << 16; b_.q = u.y & 0xffff0000u; w.z = a_.f * sc; w.w = b_.f * sc; }
        ((float4*)&At[0][0])[idx] = w;
      }
    }
    __syncthreads();
    if (c < 7){
      const int k0 = (c + 1) << 9;
      #pragma unroll
      for (int i = 0; i < 16; i++){
        int idx = t + (i << 8);
        uint2 v = make_uint2(0u, 0u);
        if (idx < 3888){
          unsigned r = (unsigned)idx / 162u;
          int fo = idx - (int)r * 162;
          int rp = p0 - 1 + (int)(r >> 2);
          int rq = q0 - 1 + (int)(r & 3);
          int kg = k0 - 68 + (fo << 2);
          if ((unsigned)rp < 64u && (unsigned)rq < 64u && (unsigned)kg <= 4092u)
            v = *(const uint2*)(attn + (((size_t)((rp << 6) + rq)) << 12) + kg);
        }
        rbuf[i] = v;
      }
    }
    #pragma unroll
    for (int j = 0; j < 4; j++){
      int y = (c << 3) + (j << 1) + (kt >> 4);
      int sa0 = (j << 7) + (kt << 2) + 68;
      float4 s = make_float4(0.f, 0.f, 0.f, 0.f);
      #pragma unroll
      for (int a = -1; a <= 1; a++){
        if ((unsigned)(y + a) < 64u){
          int rb = (pi + 1 + a) << 2;
          int sa = sa0 + (a << 6);
          float4 A0 = *(const float4*)&At[rb + qj][sa];
          float4 A1 = *(const float4*)&At[rb + qj + 1][sa];
          float4 A2 = *(const float4*)&At[rb + qj + 2][sa];
          float Lv = __shfl_up(A0.w, 1);
          float Rv = __shfl_down(A2.x, 1);
          s.x += (ktx == 0 ? 0.f : Lv) + A1.x + A2.y;
          s.y += A0.x + A1.y + A2.z;
          s.z += A0.y + A1.z + A2.w;
          s.w += A0.z + A1.w + (ktx == 15 ? 0.f : Rv);
        }
      }
      ushort4 o;
      o.x = f2bf(s.x * inv9);
      o.y = f2bf(s.y * inv9);
      o.z = f2bf(s.z * inv9);
      o.w = f2bf(s.w * inv9);
      *(ushort4*)&prow[(c << 9) + (j << 7) + (kt << 2)] = o;
    }
  }
}

// =====================================================================
// k_ygemm2: y[c,pq] = sum_l P[pq,l]*b[c,l] -- barrier-free, LDS-free.
// MFMA 16x16x32 bf16 fragments loaded DIRECTLY from global:
//   B-op (P):  lane(n,quad) reads P[pq_row(n)][kb + quad*8 ..+8] = 16B load
//   A-op (b):  lane reads b[c(n)][kb + quad*8 ..+8] = 2x float4 + pack
// Grid (64 pq-tiles, 16 K-splits) = 1024 blocks -> 4 WG/CU, 16 waves/CU;
// waves stream independently (compiler software-pipelines). K-split 16
// partials accumulated via fp32 atomics into zeroed y.
// =====================================================================
__global__ __launch_bounds__(256) void k_ygemm2(const float* __restrict__ bin,
                                                const ushort_t* __restrict__ P,
                                                float* __restrict__ y,
                                                int bt){
  const int t = threadIdx.x;
  const int lane = t & 63, wv = t >> 6;
  const int n = lane & 15, quad = lane >> 4;
  const int pq0 = blockIdx.x << 6;
  const int k0  = blockIdx.y << 8;          // 256 K per block
  const float*    bbase = bin + (((size_t)bt) << 18);
  const ushort_t* Prow  = P + (((size_t)(pq0 + (wv << 4) + n)) << 12);

  f32x4 acc[4];
  #pragma unroll
  for (int cb = 0; cb < 4; cb++) acc[cb] = (f32x4){0.f, 0.f, 0.f, 0.f};

  #pragma unroll 2
  for (int kb = k0; kb < k0 + 256; kb += 32){
    int ko = kb + (quad << 3);
    bf16x8 pf = *(const bf16x8*)(Prow + ko);
    #pragma unroll
    for (int cb = 0; cb < 4; cb++){
      const float* bp = bbase + (((cb << 4) + n) << 12) + ko;
      float4 b0 = *(const float4*)bp;
      float4 b1 = *(const float4*)(bp + 4);
      bf16x8 bf;
      bf[0] = (short)f2bf(b0.x); bf[1] = (short)f2bf(b0.y);
      bf[2] = (short)f2bf(b0.z); bf[3] = (short)f2bf(b0.w);
      bf[4] = (short)f2bf(b1.x); bf[5] = (short)f2bf(b1.y);
      bf[6] = (short)f2bf(b1.z); bf[7] = (short)f2bf(b1.w);
      acc[cb] = __builtin_amdgcn_mfma_f32_16x16x32_bf16(bf, pf, acc[cb], 0, 0, 0);
    }
  }
  int pql = pq0 + (wv << 4) + n;
  #pragma unroll
  for (int cb = 0; cb < 4; cb++)
    #pragma unroll
    for (int r = 0; r < 4; r++){
      int c = (cb << 4) + (quad << 2) + r;
      atomicAdd(&y[(((size_t)(bt * 64 + c)) << 12) + pql], acc[cb][r]);
    }
}

extern "C" void kernel_launch(void* const* d_in, const int* in_sizes, int n_in,
                              void* d_out, int out_size, void* d_ws, size_t ws_size,
                              hipStream_t stream){
  const float* f = (const float*)d_in[0];
  const float* b = (const float*)d_in[1];
  float* out  = (float*)d_out;
  float* yout = out;
  float* wout = out + 1048576;

  const size_t RB  = 4096ull * 4096 * 4;   // 64 MiB fp32 R per batch
  const size_t AB  = 4096ull * 4096 * 2;   // 32 MiB bf16 attn/P per batch

  k_prep<<<4096, 256, 0, stream>>>(b, wout, yout);   // also zeroes y

  // G1: one batch at a time. R @0 | attn @64MB | scale @96MB; P overlays R.
  float*    R     = (float*)d_ws;
  ushort_t* attn  = (ushort_t*)((char*)d_ws + RB);
  float*    scale = (float*)((char*)d_ws + RB + AB);
  ushort_t* P     = (ushort_t*)d_ws;
  for (int bt = 0; bt < 4; bt++){
    k_rgemm    <<<dim3(32, 32, 1), 256, 0, stream>>>(f, b, R, bt);
    k_softmax4 <<<512, 256, 0, stream>>>(R, attn, scale);
    k_pstencil5<<<512, 256, 0, stream>>>(attn, scale, P);
    k_ygemm2   <<<dim3(64, 16), 256, 0, stream>>>(b, P, yout, bt);
  }
}

// Round 8
// 594.551 us; speedup vs baseline: 3.4950x; 1.1151x over previous
//
#include <hip/hip_runtime.h>
#include <hip/hip_bf16.h>
#include <hip/hip_fp16.h>
#include <stdint.h>

// Problem: B=4, C=64, H=W=64, L=4096.
// Outputs: y [4,64,64,64] (1048576 f32) then w [4,4096*64,3,3] (9437184 f32).
//
// Algebra: scores[(p,q),(y,x)] = sum_{a,b in -1..1} R[(p+a,q+b),(y+a,x+b)]
//          R[uv,st] = sum_c f[c,uv]*b[c,st]        (K=64 channel GEMM, exact fp32)
//          y[c,pq]  = sum_l P[pq,l]*b[c,l]         (bf16 MFMA, barrier-free direct loads)
//          P[pq,l]  = (1/9) sum_{a,b} attn[(pq+(a,b)), l+a*64+b]
//
// attn stored UNNORMALIZED per 512-key chunk: exp(s - mref_c) + per-(row,chunk)
// scale table; k_pstencil5 applies scale per TAP-KEY'S chunk at staging time.
//
// Workspace tiers (nb = batches per group): G4 (384.5MiB) / G2 (192.25) / G1 (96.125).
// Per-batch strides: R 16777216 f32 | attn 16777216 bf16 | scale 32768 f32;
// P overlays R (stride 33554432 bf16 within R's 64MiB slot).

typedef unsigned short ushort_t;
typedef __attribute__((ext_vector_type(8))) short bf16x8;
typedef __attribute__((ext_vector_type(4))) float f32x4;

#define RSTRIDE  16777216ull   // floats per batch (R)
#define ASTRIDE  16777216ull   // ushorts per batch (attn)
#define PSTRIDE  33554432ull   // ushorts per batch slot for P (overlays R's 64MiB)
#define SSTRIDE  32768ull      // floats per batch (scale)

__device__ __forceinline__ float bf2f(ushort_t u){
  union { float f; uint32_t i; } v; v.i = ((uint32_t)u) << 16; return v.f;
}
__device__ __forceinline__ ushort_t f2bf(float f){
  union { float f; uint32_t i; } v; v.f = f;
  uint32_t x = v.i;
  return (ushort_t)((x + 0x7fffu + ((x >> 16) & 1u)) >> 16);  // RNE
}

// ---- k_prep2: w output via LDS slab + coalesced float4 dump; zero y ----
__global__ __launch_bounds__(256) void k_prep2(const float* __restrict__ bin,
                                               float* __restrict__ wout,
                                               float* __restrict__ yzero){
  __shared__ float ls[2304];                     // 256 threads x 9 floats
  int tid = threadIdx.x;
  int t = blockIdx.x * 256 + tid;                // (bb, l, c), c fastest
  yzero[t] = 0.f;
  int c  = t & 63;
  int l  = (t >> 6) & 4095;
  int bb = t >> 18;
  int y = l >> 6, x = l & 63;
  const float* src = bin + (((size_t)(bb * 64 + c)) << 12);
  float* dst = ls + tid * 9;
  #pragma unroll
  for (int i = 0; i < 3; i++){
    int yy = y + i - 1;
    #pragma unroll
    for (int j = 0; j < 3; j++){
      int xx = x + j - 1;
      float v = 0.f;
      if ((unsigned)yy < 64u && (unsigned)xx < 64u) v = src[(yy << 6) + xx];
      dst[i * 3 + j] = v;
    }
  }
  __syncthreads();
  float* wbase = wout + (size_t)blockIdx.x * 2304;
  #pragma unroll
  for (int idx = tid; idx < 576; idx += 256)
    *(float4*)(wbase + (idx << 2)) = *(const float4*)(ls + (idx << 2));
}

// ---- k_rgemm: R[m,n] = sum_c f[c,m] * b[c,n]  (fp32 exact), 128x128 tile ----
__global__ __launch_bounds__(256, 2) void k_rgemm(const float* __restrict__ f,
                                                  const float* __restrict__ bin,
                                                  float* __restrict__ R,
                                                  int bt0){
  __shared__ float As[64][128];
  __shared__ float Bs[64][128];
  int bt = bt0 + blockIdx.z;
  int m0 = blockIdx.x << 7;
  int n0 = blockIdx.y << 7;
  const float* fb = f   + (((size_t)bt) << 18);
  const float* bb = bin + (((size_t)bt) << 18);
  float* Rb = R + (size_t)blockIdx.z * RSTRIDE;
  int t = threadIdx.x;
  for (int idx = t; idx < 64 * 128; idx += 256){
    int c = idx >> 7, m = idx & 127;
    As[c][m] = fb[(c << 12) + m0 + m];
    Bs[c][m] = bb[(c << 12) + n0 + m];
  }
  __syncthreads();
  int tx = t & 15, ty = t >> 4;
  float acc[8][8];
  #pragma unroll
  for (int i = 0; i < 8; i++)
    #pragma unroll
    for (int j = 0; j < 8; j++) acc[i][j] = 0.f;

  for (int c = 0; c < 64; c++){
    float4 a0 = *(const float4*)&As[c][(ty << 3)];
    float4 a1 = *(const float4*)&As[c][(ty << 3) + 4];
    float4 b0 = *(const float4*)&Bs[c][(tx << 2)];
    float4 b1 = *(const float4*)&Bs[c][64 + (tx << 2)];
    float av[8] = {a0.x, a0.y, a0.z, a0.w, a1.x, a1.y, a1.z, a1.w};
    float bv[8] = {b0.x, b0.y, b0.z, b0.w, b1.x, b1.y, b1.z, b1.w};
    #pragma unroll
    for (int i = 0; i < 8; i++)
      #pragma unroll
      for (int j = 0; j < 8; j++) acc[i][j] += av[i] * bv[j];
  }
  #pragma unroll
  for (int i = 0; i < 8; i++){
    float* dst = Rb + ((size_t)(m0 + (ty << 3) + i) << 12) + n0;
    *(float4*)(dst + (tx << 2))      = make_float4(acc[i][0], acc[i][1], acc[i][2], acc[i][3]);
    *(float4*)(dst + 64 + (tx << 2)) = make_float4(acc[i][4], acc[i][5], acc[i][6], acc[i][7]);
  }
}

// =====================================================================
// k_softmax4: fused single-pass stencil + online softmax. blockIdx.y = batch.
// =====================================================================
__global__ __launch_bounds__(256, 2) void k_softmax4(const float* __restrict__ Rg,
                                                     ushort_t* __restrict__ attng,
                                                     float* __restrict__ scaleg){
  __shared__ float Rt[24][648];                 // 62208 B
  const int t  = threadIdx.x;
  const int bb = blockIdx.x;
  const float* R = Rg + (size_t)blockIdx.y * RSTRIDE;
  ushort_t* attn = attng + (size_t)blockIdx.y * ASTRIDE;
  float* scale = scaleg + (size_t)blockIdx.y * SSTRIDE;
  const int inner = bb >> 3;
  const int ty = ((bb & 7) << 1) | (inner & 1); // XCD band swizzle
  const int tx = inner >> 1;
  const int p0 = ty << 2, q0 = tx << 1;
  const int qi = t >> 5, kt = t & 31;
  const int pi = qi >> 1, qj = qi & 1;
  const int ktx = kt & 15;

  float M = -3.0e38f, L = 0.f;
  float mref[8];
  float4 rbuf[16];

  int row = ((p0 + pi) << 6) + q0 + qj;
  ushort_t* arow = attn + ((size_t)row << 12);

  // prefetch chunk 0
  #pragma unroll
  for (int i = 0; i < 16; i++){
    int idx = t + (i << 8);
    float4 v = make_float4(0.f, 0.f, 0.f, 0.f);
    if (idx < 3888){
      unsigned r = (unsigned)idx / 162u;
      int fo = idx - (int)r * 162;
      int rp = p0 - 1 + (int)(r >> 2);
      int rq = q0 - 1 + (int)(r & 3);
      int kg = -68 + (fo << 2);
      if ((unsigned)rp < 64u && (unsigned)rq < 64u && (unsigned)kg <= 4092u)
        v = *(const float4*)(R + (((size_t)((rp << 6) + rq)) << 12) + kg);
    }
    rbuf[i] = v;
  }

  #pragma unroll
  for (int c = 0; c < 8; c++){
    __syncthreads();
    #pragma unroll
    for (int i = 0; i < 16; i++){
      int idx = t + (i << 8);
      if (idx < 3888) ((float4*)&Rt[0][0])[idx] = rbuf[i];
    }
    __syncthreads();
    if (c < 7){
      const int k0 = (c + 1) << 9;
      #pragma unroll
      for (int i = 0; i < 16; i++){
        int idx = t + (i << 8);
        float4 v = make_float4(0.f, 0.f, 0.f, 0.f);
        if (idx < 3888){
          unsigned r = (unsigned)idx / 162u;
          int fo = idx - (int)r * 162;
          int rp = p0 - 1 + (int)(r >> 2);
          int rq = q0 - 1 + (int)(r & 3);
          int kg = k0 - 68 + (fo << 2);
          if ((unsigned)rp < 64u && (unsigned)rq < 64u && (unsigned)kg <= 4092u)
            v = *(const float4*)(R + (((size_t)((rp << 6) + rq)) << 12) + kg);
        }
        rbuf[i] = v;
      }
    }
    // 9-tap stencil from LDS; +-1 key edges via cross-lane shfl
    float4 sv[4];
    #pragma unroll
    for (int j = 0; j < 4; j++){
      int y = (c << 3) + (j << 1) + (kt >> 4);
      int sa0 = (j << 7) + (kt << 2) + 68;
      float4 s = make_float4(0.f, 0.f, 0.f, 0.f);
      #pragma unroll
      for (int a = -1; a <= 1; a++){
        if ((unsigned)(y + a) < 64u){
          int rb = (pi + 1 + a) << 2;
          int sa = sa0 + (a << 6);
          float4 A0 = *(const float4*)&Rt[rb + qj][sa];
          float4 A1 = *(const float4*)&Rt[rb + qj + 1][sa];
          float4 A2 = *(const float4*)&Rt[rb + qj + 2][sa];
          float Lv = __shfl_up(A0.w, 1);
          float Rv = __shfl_down(A2.x, 1);
          s.x += (ktx == 0 ? 0.f : Lv) + A1.x + A2.y;
          s.y += A0.x + A1.y + A2.z;
          s.z += A0.y + A1.z + A2.w;
          s.w += A0.z + A1.w + (ktx == 15 ? 0.f : Rv);
        }
      }
      s.x *= 10.f; s.y *= 10.f; s.z *= 10.f; s.w *= 10.f;
      sv[j] = s;
    }
    // lane-uniform chunk max over this query's 32 lanes
    float mc = M;
    #pragma unroll
    for (int j = 0; j < 4; j++)
      mc = fmaxf(mc, fmaxf(fmaxf(sv[j].x, sv[j].y), fmaxf(sv[j].z, sv[j].w)));
    #pragma unroll
    for (int off = 1; off < 32; off <<= 1) mc = fmaxf(mc, __shfl_xor(mc, off));
    // online update + immediate unnormalized bf16 store
    float lnew = L * __expf(M - mc);
    #pragma unroll
    for (int j = 0; j < 4; j++){
      float ex = __expf(sv[j].x - mc), ey = __expf(sv[j].y - mc);
      float ez = __expf(sv[j].z - mc), ew = __expf(sv[j].w - mc);
      lnew += ex + ey + ez + ew;
      ushort4 o; o.x = f2bf(ex); o.y = f2bf(ey); o.z = f2bf(ez); o.w = f2bf(ew);
      *(ushort4*)&arow[(c << 9) + (j << 7) + (kt << 2)] = o;
    }
    L = lnew; M = mc; mref[c] = mc;
  }
  // L per-lane partial; M/mref lane-uniform -> plain cross-lane sum
  #pragma unroll
  for (int off = 1; off < 32; off <<= 1) L += __shfl_xor(L, off);
  if (kt == 0){
    float invL = 1.0f / L;
    float4 s0, s1;
    s0.x = __expf(mref[0] - M) * invL; s0.y = __expf(mref[1] - M) * invL;
    s0.z = __expf(mref[2] - M) * invL; s0.w = __expf(mref[3] - M) * invL;
    s1.x = __expf(mref[4] - M) * invL; s1.y = __expf(mref[5] - M) * invL;
    s1.z = __expf(mref[6] - M) * invL; s1.w = __expf(mref[7] - M) * invL;
    *(float4*)&scale[(row << 3)]     = s0;
    *(float4*)&scale[(row << 3) + 4] = s1;
  }
}

// =====================================================================
// k_pstencil5: P = (1/9)*stencil9(attn_unnorm * scale), scale per tap-key
// chunk at staging. blockIdx.y = batch.
// =====================================================================
__global__ __launch_bounds__(256, 2) void k_pstencil5(const ushort_t* __restrict__ attng,
                                                      const float* __restrict__ scaleg,
                                                      ushort_t* __restrict__ Pg){
  __shared__ float At[24][648];                 // 62208 B
  __shared__ float Sc[24][8];                   // 768 B
  const int t  = threadIdx.x;
  const int bb = blockIdx.x;
  const ushort_t* attn = attng + (size_t)blockIdx.y * ASTRIDE;
  const float* scale = scaleg + (size_t)blockIdx.y * SSTRIDE;
  ushort_t* P = Pg + (size_t)blockIdx.y * PSTRIDE;
  const int inner = bb >> 3;
  const int ty = ((bb & 7) << 1) | (inner & 1);
  const int tx = inner >> 1;
  const int p0 = ty << 2, q0 = tx << 1;
  const int qi = t >> 5, kt = t & 31;
  const int pi = qi >> 1, qj = qi & 1;
  const int ktx = kt & 15;

  int row = ((p0 + pi) << 6) + q0 + qj;
  ushort_t* prow = P + ((size_t)row << 12);
  const float inv9 = 1.0f / 9.0f;

  if (t < 192){
    int r = t >> 3, cc = t & 7;
    int rp = p0 - 1 + (r >> 2);
    int rq = q0 - 1 + (r & 3);
    float v = 0.f;
    if ((unsigned)rp < 64u && (unsigned)rq < 64u)
      v = scale[(((rp << 6) + rq) << 3) + cc];
    Sc[r][cc] = v;
  }

  uint2 rbuf[16];
  #pragma unroll
  for (int i = 0; i < 16; i++){
    int idx = t + (i << 8);
    uint2 v = make_uint2(0u, 0u);
    if (idx < 3888){
      unsigned r = (unsigned)idx / 162u;
      int fo = idx - (int)r * 162;
      int rp = p0 - 1 + (int)(r >> 2);
      int rq = q0 - 1 + (int)(r & 3);
      int kg = -68 + (fo << 2);
      if ((unsigned)rp < 64u && (unsigned)rq < 64u && (unsigned)kg <= 4092u)
        v = *(const uint2*)(attn + (((size_t)((rp << 6) + rq)) << 12) + kg);
    }
    rbuf[i] = v;
  }

  #pragma unroll
  for (int c = 0; c < 8; c++){
    __syncthreads();   // first iter also fences the Sc stores
    #pragma unroll
    for (int i = 0; i < 16; i++){
      int idx = t + (i << 8);
      if (idx < 3888){
        unsigned r = (unsigned)idx / 162u;
        int fo = idx - (int)r * 162;
        int key = (c << 9) - 68 + (fo << 2);
        key = key < 0 ? 0 : (key > 4095 ? 4095 : key);
        float sc = Sc[r][key >> 9];
        uint2 u = rbuf[i];
        float4 w;
        { union { uint32_t q; float f; } a_, b_;
          a_.q = u.x << 16; b_.q = u.x & 0xffff0000u; w.x = a_.f * sc; w.y = b_.f * sc; }
        { union { uint32_t q; float f; } a_, b_;
          a_.q = u.y << 16; b_.q = u.y & 0xffff0000u; w.z = a_.f * sc; w.w = b_.f * sc; }
        ((float4*)&At[0][0])[idx] = w;
      }
    }
    __syncthreads();
    if (c < 7){
      const int k0 = (c + 1) << 9;
      #pragma unroll
      for (int i = 0; i < 16; i++){
        int idx = t + (i << 8);
        uint2 v = make_uint2(0u, 0u);
        if (idx < 3888){
          unsigned r = (unsigned)idx / 162u;
          int fo = idx - (int)r * 162;
          int rp = p0 - 1 + (int)(r >> 2);
          int rq = q0 - 1 + (int)(r & 3);
          int kg = k0 - 68 + (fo << 2);
          if ((unsigned)rp < 64u && (unsigned)rq < 64u && (unsigned)kg <= 4092u)
            v = *(const uint2*)(attn + (((size_t)((rp << 6) + rq)) << 12) + kg);
        }
        rbuf[i] = v;
      }
    }
    #pragma unroll
    for (int j = 0; j < 4; j++){
      int y = (c << 3) + (j << 1) + (kt >> 4);
      int sa0 = (j << 7) + (kt << 2) + 68;
      float4 s = make_float4(0.f, 0.f, 0.f, 0.f);
      #pragma unroll
      for (int a = -1; a <= 1; a++){
        if ((unsigned)(y + a) < 64u){
          int rb = (pi + 1 + a) << 2;
          int sa = sa0 + (a << 6);
          float4 A0 = *(const float4*)&At[rb + qj][sa];
          float4 A1 = *(const float4*)&At[rb + qj + 1][sa];
          float4 A2 = *(const float4*)&At[rb + qj + 2][sa];
          float Lv = __shfl_up(A0.w, 1);
          float Rv = __shfl_down(A2.x, 1);
          s.x += (ktx == 0 ? 0.f : Lv) + A1.x + A2.y;
          s.y += A0.x + A1.y + A2.z;
          s.z += A0.y + A1.z + A2.w;
          s.w += A0.z + A1.w + (ktx == 15 ? 0.f : Rv);
        }
      }
      ushort4 o;
      o.x = f2bf(s.x * inv9);
      o.y = f2bf(s.y * inv9);
      o.z = f2bf(s.z * inv9);
      o.w = f2bf(s.w * inv9);
      *(ushort4*)&prow[(c << 9) + (j << 7) + (kt << 2)] = o;
    }
  }
}

// =====================================================================
// k_ygemm2: y[c,pq] = sum_l P[pq,l]*b[c,l] -- barrier-free, LDS-free,
// MFMA fragments loaded directly from global. blockIdx.z = batch.
// =====================================================================
__global__ __launch_bounds__(256) void k_ygemm2(const float* __restrict__ bin,
                                                const ushort_t* __restrict__ Pg,
                                                float* __restrict__ y,
                                                int bt0){
  const int t = threadIdx.x;
  const int lane = t & 63, wv = t >> 6;
  const int n = lane & 15, quad = lane >> 4;
  const int bt = bt0 + blockIdx.z;
  const int pq0 = blockIdx.x << 6;
  const int k0  = blockIdx.y << 8;          // 256 K per block
  const float*    bbase = bin + (((size_t)bt) << 18);
  const ushort_t* Prow  = Pg + (size_t)blockIdx.z * PSTRIDE
                             + (((size_t)(pq0 + (wv << 4) + n)) << 12);

  f32x4 acc[4];
  #pragma unroll
  for (int cb = 0; cb < 4; cb++) acc[cb] = (f32x4){0.f, 0.f, 0.f, 0.f};

  #pragma unroll 2
  for (int kb = k0; kb < k0 + 256; kb += 32){
    int ko = kb + (quad << 3);
    bf16x8 pf = *(const bf16x8*)(Prow + ko);
    #pragma unroll
    for (int cb = 0; cb < 4; cb++){
      const float* bp = bbase + (((cb << 4) + n) << 12) + ko;
      float4 b0 = *(const float4*)bp;
      float4 b1 = *(const float4*)(bp + 4);
      bf16x8 bf;
      bf[0] = (short)f2bf(b0.x); bf[1] = (short)f2bf(b0.y);
      bf[2] = (short)f2bf(b0.z); bf[3] = (short)f2bf(b0.w);
      bf[4] = (short)f2bf(b1.x); bf[5] = (short)f2bf(b1.y);
      bf[6] = (short)f2bf(b1.z); bf[7] = (short)f2bf(b1.w);
      acc[cb] = __builtin_amdgcn_mfma_f32_16x16x32_bf16(bf, pf, acc[cb], 0, 0, 0);
    }
  }
  int pql = pq0 + (wv << 4) + n;
  #pragma unroll
  for (int cb = 0; cb < 4; cb++)
    #pragma unroll
    for (int r = 0; r < 4; r++){
      int c = (cb << 4) + (quad << 2) + r;
      atomicAdd(&y[(((size_t)(bt * 64 + c)) << 12) + pql], acc[cb][r]);
    }
}

extern "C" void kernel_launch(void* const* d_in, const int* in_sizes, int n_in,
                              void* d_out, int out_size, void* d_ws, size_t ws_size,
                              hipStream_t stream){
  const float* f = (const float*)d_in[0];
  const float* b = (const float*)d_in[1];
  float* out  = (float*)d_out;
  float* yout = out;
  float* wout = out + 1048576;

  const size_t RB  = RSTRIDE * 4;   // 64 MiB fp32 R per batch
  const size_t AB  = ASTRIDE * 2;   // 32 MiB bf16 attn per batch
  const size_t SCB = SSTRIDE * 4;   // 128 KiB scale per batch
  const size_t PER = RB + AB + SCB;

  int nb = 1;
  if (ws_size >= 4 * PER) nb = 4;
  else if (ws_size >= 2 * PER) nb = 2;

  k_prep2<<<4096, 256, 0, stream>>>(b, wout, yout);   // also zeroes y

  // Layout per group: R[nb] @0 | attn[nb] @nb*RB | scale[nb] @nb*(RB+AB); P overlays R.
  float*    R     = (float*)d_ws;
  ushort_t* attn  = (ushort_t*)((char*)d_ws + (size_t)nb * RB);
  float*    scale = (float*)((char*)d_ws + (size_t)nb * (RB + AB));
  ushort_t* P     = (ushort_t*)d_ws;
  for (int bt0 = 0; bt0 < 4; bt0 += nb){
    k_rgemm    <<<dim3(32, 32, nb), 256, 0, stream>>>(f, b, R, bt0);
    k_softmax4 <<<dim3(512, nb),    256, 0, stream>>>(R, attn, scale);
    k_pstencil5<<<dim3(512, nb),    256, 0, stream>>>(attn, scale, P);
    k_ygemm2   <<<dim3(64, 16, nb), 256, 0, stream>>>(b, P, yout, bt0);
  }
}